// Round 15
// baseline (52093.860 us; speedup 1.0000x reference)
//
#include <hip/hip_runtime.h>
#include <math.h>

#define TMAX 200
#define CB   64

__device__ __forceinline__ float sig_(float x){ return 1.0f/(1.0f+expf(-x)); }

// Light cluster barrier: one atomicAdd + go flag, single poller per block.
__device__ __forceinline__ void cl_sync(int* cnt, int* go, int nblk, int ep, int tid)
{
    __syncthreads();
    if (tid == 0) {
        __threadfence();
        int old = __hip_atomic_fetch_add(cnt, 1, __ATOMIC_ACQ_REL, __HIP_MEMORY_SCOPE_AGENT);
        if (old == nblk - 1) {
            __hip_atomic_store(cnt, 0, __ATOMIC_RELAXED, __HIP_MEMORY_SCOPE_AGENT);
            __hip_atomic_store(go, ep, __ATOMIC_RELEASE, __HIP_MEMORY_SCOPE_AGENT);
        } else {
            while (__hip_atomic_load(go, __ATOMIC_ACQUIRE, __HIP_MEMORY_SCOPE_AGENT) < ep)
                __builtin_amdgcn_s_sleep(16);
        }
        __threadfence();
    }
    __syncthreads();
}

// LDS floats:
//  A: XS[2][32][68] @0/@2176 ; WS_A[2][48][36] @4352/@6080     (7808)
//  B: XS[2][32][68] @0/@2176 ; WS_B[2][32][36] @4352/@5504     (6656)
//  C: XS[2][2][32][68] @0/@4352 ; WS_C[2][8][36] @8704/@8992   (9280)
//  AUX @9280: A hb[16][68]=1088 ; C pb[8][68]=544
#define LDSF 10368

__global__ __launch_bounds__(256, 2)
void kfused(const int* __restrict__ lengths,
            const float* __restrict__ eps,
            const float* __restrict__ W_ih, const float* __restrict__ b_ih,
            const float* __restrict__ b_hh,
            const float* __restrict__ W1a, const float* __restrict__ b1a,
            const float* __restrict__ W1b, const float* __restrict__ b1b,
            const float* __restrict__ W2a, const float* __restrict__ b2a,
            const float* __restrict__ W2b, const float* __restrict__ b2b,
            float* __restrict__ out_p1, float* __restrict__ out_p2, float* __restrict__ out_h,
            int* __restrict__ bar, float* __restrict__ xT, float* __restrict__ hT,
            float* __restrict__ haT, int nblk)
{
    __shared__ float lds[LDSF];
    __shared__ int sbs[TMAX], soff[TMAX];

    const int tid = threadIdx.x;
    const int bid = blockIdx.x;
    const int wv  = __builtin_amdgcn_readfirstlane(tid >> 6);   // 0..3
    const int l   = tid & 63;            // lane = batch within cluster
    // XCD mapping (R14-proven): rank r same across clusters -> same XCD -> weight
    // slice L2-resident (grid = 8*nblk, nblk % 8 == 0).
    const int cl  = bid / nblk;
    const int r   = bid % nblk;
    const int cb  = cl * CB;

    int* cnt = &bar[cl * 64];
    int* go  = &bar[cl * 64 + 16];

    if (tid < TMAX) {
        int c = 0;
        for (int b = 0; b < 512; ++b) c += (lengths[b] > tid) ? 1 : 0;
        sbs[tid] = c;
    }
    __syncthreads();
    if (tid == 0) { int a = 0; for (int i = 0; i < TMAX; ++i) { soff[i] = a; a += sbs[i]; } }
    __syncthreads();

    for (int t = 0; t < TMAX; ++t) {
        const int bsz = sbs[t], ofs = soff[t];

        // ===== phase A: gi = x@W_ih^T -> GRU (in-register) -> h ; 64 units x 16 j =====
        for (int s = r; s < 64; s += nblk) {
            const int j0 = s * 16;
            float acc[12];
            #pragma unroll
            for (int i = 0; i < 12; ++i) acc[i] = 0.f;

            if (t > 0) {
                const int xk = tid >> 3, xb = (tid & 7) * 8;
                const int wk4 = (tid & 7) * 4;
                const int w0row = tid >> 3;                 // 0..31 (gates r,z)
                const int w0g = w0row >> 4, w0j = w0row & 15;
                const int w1row = 32 + (tid >> 3);          // 32..47 (gate n), tid<128
                const int w1j = w1row & 15;
                float4 px0, px1, pw0, pw1;
                {
                    const float* xp = &xT[(size_t)xk * 512 + cb + xb];
                    px0 = *(const float4*)xp; px1 = *(const float4*)(xp + 4);
                    pw0 = *(const float4*)&W_ih[(size_t)(w0g*1024 + j0 + w0j) * 256 + wk4];
                    if (tid < 128)
                        pw1 = *(const float4*)&W_ih[(size_t)(2048 + j0 + w1j) * 256 + wk4];
                }
                for (int kc = 0; kc < 8; ++kc) {
                    float* xs = lds + (kc & 1) * 2176;
                    float* ws = lds + 4352 + (kc & 1) * 1728;
                    *(float4*)&xs[xk * 68 + xb]     = px0;
                    *(float4*)&xs[xk * 68 + xb + 4] = px1;
                    *(float4*)&ws[w0row * 36 + wk4] = pw0;
                    if (tid < 128) *(float4*)&ws[w1row * 36 + wk4] = pw1;
                    __syncthreads();
                    if (kc < 7) {
                        const int kb = (kc + 1) * 32;
                        const float* xp = &xT[(size_t)(kb + xk) * 512 + cb + xb];
                        px0 = *(const float4*)xp; px1 = *(const float4*)(xp + 4);
                        pw0 = *(const float4*)&W_ih[(size_t)(w0g*1024 + j0 + w0j) * 256 + kb + wk4];
                        if (tid < 128)
                            pw1 = *(const float4*)&W_ih[(size_t)(2048 + j0 + w1j) * 256 + kb + wk4];
                    }
                    #pragma unroll
                    for (int k4 = 0; k4 < 8; ++k4) {
                        const float a0 = xs[(k4*4+0)*68 + l];
                        const float a1 = xs[(k4*4+1)*68 + l];
                        const float a2 = xs[(k4*4+2)*68 + l];
                        const float a3 = xs[(k4*4+3)*68 + l];
                        #pragma unroll
                        for (int jq = 0; jq < 4; ++jq) {
                            #pragma unroll
                            for (int g = 0; g < 3; ++g) {
                                const float4 w = *(const float4*)&ws[(g*16 + wv*4 + jq)*36 + k4*4];
                                acc[jq*3+g] = fmaf(a3,w.w,fmaf(a2,w.z,
                                               fmaf(a1,w.y,fmaf(a0,w.x,acc[jq*3+g]))));
                            }
                        }
                    }
                }
            }
            // GRU fully in registers
            #pragma unroll
            for (int jq = 0; jq < 4; ++jq) {
                const int j = j0 + wv * 4 + jq;
                const float rr = sig_(acc[jq*3+0] + b_ih[j] + b_hh[j]);
                const float zz = sig_(acc[jq*3+1] + b_ih[1024+j] + b_hh[1024+j]);
                const float nn = tanhf(acc[jq*3+2] + b_ih[2048+j] + rr * b_hh[2048+j]);
                const float h = (1.f - zz) * nn;
                hT[(size_t)j * 512 + cb + l] = h;          // coalesced b32
                lds[9280 + (wv*4+jq)*68 + l] = h;
            }
            __syncthreads();
            {   // out_h bounce (coalesced rows)
                const int b = tid >> 2, jj = tid & 3;
                if (cb + b < bsz) {
                    float4 v = { lds[9280+(jj*4+0)*68+b], lds[9280+(jj*4+1)*68+b],
                                 lds[9280+(jj*4+2)*68+b], lds[9280+(jj*4+3)*68+b] };
                    *(float4*)&out_h[(size_t)(ofs+cb+b)*1024 + j0 + jj*4] = v;
                }
            }
            __syncthreads();
        }
        cl_sync(cnt, go, nblk, t * 3 + 1, tid);

        // ===== phase B: ha = tanh(h@Wa^T + ba) ; 64 units x 32 n =====
        for (int s = r; s < 64; s += nblk) {
            const int n0 = s * 32;
            const float* __restrict__ Wa = (n0 < 1024) ? W1a : W2a;
            const float* __restrict__ ba = (n0 < 1024) ? b1a : b2a;
            const int nr0 = n0 & 1023;
            float acc[8];
            #pragma unroll
            for (int i = 0; i < 8; ++i) acc[i] = 0.f;
            const int xk = tid >> 3, xb = (tid & 7) * 8;
            const int wrow = tid >> 3, wk4 = (tid & 7) * 4;
            float4 px0, px1, pw;
            {
                const float* xp = &hT[(size_t)xk * 512 + cb + xb];
                px0 = *(const float4*)xp; px1 = *(const float4*)(xp + 4);
                pw = *(const float4*)&Wa[(size_t)(nr0 + wrow) * 1024 + wk4];
            }
            for (int kc = 0; kc < 32; ++kc) {
                float* xs = lds + (kc & 1) * 2176;
                float* ws = lds + 4352 + (kc & 1) * 1152;
                *(float4*)&xs[xk * 68 + xb]     = px0;
                *(float4*)&xs[xk * 68 + xb + 4] = px1;
                *(float4*)&ws[wrow * 36 + wk4]  = pw;
                __syncthreads();
                if (kc < 31) {
                    const int kb = (kc + 1) * 32;
                    const float* xp = &hT[(size_t)(kb + xk) * 512 + cb + xb];
                    px0 = *(const float4*)xp; px1 = *(const float4*)(xp + 4);
                    pw = *(const float4*)&Wa[(size_t)(nr0 + wrow) * 1024 + kb + wk4];
                }
                #pragma unroll
                for (int k4 = 0; k4 < 8; ++k4) {
                    const float a0 = xs[(k4*4+0)*68 + l];
                    const float a1 = xs[(k4*4+1)*68 + l];
                    const float a2 = xs[(k4*4+2)*68 + l];
                    const float a3 = xs[(k4*4+3)*68 + l];
                    #pragma unroll
                    for (int q = 0; q < 8; ++q) {
                        const float4 w = *(const float4*)&ws[(wv*8+q)*36 + k4*4];
                        acc[q] = fmaf(a3,w.w,fmaf(a2,w.z,fmaf(a1,w.y,fmaf(a0,w.x,acc[q]))));
                    }
                }
            }
            #pragma unroll
            for (int q = 0; q < 8; ++q)
                haT[(size_t)(n0 + wv*8 + q) * 512 + cb + l] =
                    tanhf(acc[q] + ba[nr0 + wv*8 + q]);    // coalesced b32, no LDS epi
        }
        cl_sync(cnt, go, nblk, t * 3 + 2, tid);

        // ===== phase C: p = ha@Wb^T + bb ; 64 units x 4 cols (both fams) =====
        for (int s = r; s < 64; s += nblk) {
            const int c0 = s * 4;
            const int fam = wv >> 1, cg = wv & 1;
            float acc0 = 0.f, acc1 = 0.f;
            const int xk = tid >> 3, xb = (tid & 7) * 8;
            const int wrow = tid >> 3, wk4 = (tid & 7) * 4;   // valid rows 0..7 (tid<64)
            float4 pa0, pa1, pc0, pc1, pw;
            pw = make_float4(0.f, 0.f, 0.f, 0.f);
            {
                const float* p0 = &haT[(size_t)xk * 512 + cb + xb];
                const float* p1 = &haT[(size_t)(1024 + xk) * 512 + cb + xb];
                pa0 = *(const float4*)p0; pa1 = *(const float4*)(p0 + 4);
                pc0 = *(const float4*)p1; pc1 = *(const float4*)(p1 + 4);
                if (tid < 64)
                    pw = (wrow < 4)
                        ? *(const float4*)&W1b[(size_t)(c0 + wrow) * 1024 + wk4]
                        : *(const float4*)&W2b[(size_t)(c0 + wrow - 4) * 1024 + wk4];
            }
            for (int kc = 0; kc < 32; ++kc) {
                float* xsb = lds + (kc & 1) * 4352;
                float* ws  = lds + 8704 + (kc & 1) * 288;
                *(float4*)&xsb[xk * 68 + xb]            = pa0;
                *(float4*)&xsb[xk * 68 + xb + 4]        = pa1;
                *(float4*)&xsb[2176 + xk * 68 + xb]     = pc0;
                *(float4*)&xsb[2176 + xk * 68 + xb + 4] = pc1;
                if (tid < 64) *(float4*)&ws[wrow * 36 + wk4] = pw;
                __syncthreads();
                if (kc < 31) {
                    const int kb = (kc + 1) * 32;
                    const float* p0 = &haT[(size_t)(kb + xk) * 512 + cb + xb];
                    const float* p1 = &haT[(size_t)(1024 + kb + xk) * 512 + cb + xb];
                    pa0 = *(const float4*)p0; pa1 = *(const float4*)(p0 + 4);
                    pc0 = *(const float4*)p1; pc1 = *(const float4*)(p1 + 4);
                    if (tid < 64)
                        pw = (wrow < 4)
                            ? *(const float4*)&W1b[(size_t)(c0 + wrow) * 1024 + kb + wk4]
                            : *(const float4*)&W2b[(size_t)(c0 + wrow - 4) * 1024 + kb + wk4];
                }
                const float* xsf = xsb + fam * 2176;
                #pragma unroll
                for (int k4 = 0; k4 < 8; ++k4) {
                    const float a0 = xsf[(k4*4+0)*68 + l];
                    const float a1 = xsf[(k4*4+1)*68 + l];
                    const float a2 = xsf[(k4*4+2)*68 + l];
                    const float a3 = xsf[(k4*4+3)*68 + l];
                    const float4 w0 = *(const float4*)&ws[(fam*4 + cg*2 + 0)*36 + k4*4];
                    const float4 w1 = *(const float4*)&ws[(fam*4 + cg*2 + 1)*36 + k4*4];
                    acc0 = fmaf(a3,w0.w,fmaf(a2,w0.z,fmaf(a1,w0.y,fmaf(a0,w0.x,acc0))));
                    acc1 = fmaf(a3,w1.w,fmaf(a2,w1.z,fmaf(a1,w1.y,fmaf(a0,w1.x,acc1))));
                }
            }
            {   // exchange p (+bias) across fams
                const float bias0 = fam ? b2b[c0 + cg*2 + 0] : b1b[c0 + cg*2 + 0];
                const float bias1 = fam ? b2b[c0 + cg*2 + 1] : b1b[c0 + cg*2 + 1];
                lds[9280 + (fam*4 + cg*2 + 0)*68 + l] = acc0 + bias0;
                lds[9280 + (fam*4 + cg*2 + 1)*68 + l] = acc1 + bias1;
            }
            __syncthreads();
            if (wv < 2) {        // fam0 waves: x-fuse (cg == wv)
                #pragma unroll
                for (int q = 0; q < 2; ++q) {
                    const int c = c0 + wv*2 + q;
                    const float p1v = lds[9280 + (wv*2+q)*68 + l];
                    const float p2v = lds[9280 + (4 + wv*2+q)*68 + l];
                    const float e = eps[(size_t)t * 131072 + (size_t)(cb + l) * 256 + c];
                    xT[(size_t)c * 512 + cb + l] = fmaf(expf(0.5f * p2v), e, p1v);
                }
            } else {             // fam1 waves: p scatter
                const int idx = tid - 128;
                const int fm = idx & 1, b = idx >> 1;
                if (cb + b < bsz) {
                    float4 v = { lds[9280+(fm*4+0)*68+b], lds[9280+(fm*4+1)*68+b],
                                 lds[9280+(fm*4+2)*68+b], lds[9280+(fm*4+3)*68+b] };
                    float* __restrict__ dst = fm ? out_p2 : out_p1;
                    *(float4*)&dst[(size_t)(ofs + cb + b) * 256 + c0] = v;
                }
            }
            __syncthreads();
        }
        cl_sync(cnt, go, nblk, t * 3 + 3, tid);
    }
}

extern "C" void kernel_launch(void* const* d_in, const int* in_sizes, int n_in,
                              void* d_out, int out_size, void* d_ws, size_t ws_size,
                              hipStream_t stream)
{
    (void)in_sizes; (void)n_in; (void)ws_size;
    const int*   lengths = (const int*)  d_in[1];
    const float* eps     = (const float*)d_in[2];
    const float* W_ih    = (const float*)d_in[5];
    const float* b_ih    = (const float*)d_in[6];
    const float* b_hh    = (const float*)d_in[8];
    const float* W1a     = (const float*)d_in[9];
    const float* b1a     = (const float*)d_in[10];
    const float* W1b     = (const float*)d_in[11];
    const float* b1b     = (const float*)d_in[12];
    const float* W2a     = (const float*)d_in[13];
    const float* b2a     = (const float*)d_in[14];
    const float* W2b     = (const float*)d_in[15];
    const float* b2b     = (const float*)d_in[16];

    float* out = (float*)d_out;
    const size_t N = (size_t)out_size / 1536;
    float* out_p1 = out;
    float* out_p2 = out + N * 256;
    float* out_h  = out + N * 512;

    int*   bar = (int*)d_ws;                      // 4 KB barrier region
    float* xT  = (float*)((char*)d_ws + 4096);    // [256][512]
    float* hT  = xT + 131072;                     // [1024][512]
    float* haT = hT + 524288;                     // [2048][512]  (~6.8 MB total)

    hipMemsetAsync(d_ws, 0, 4096, stream);

    int dev = 0;
    (void)hipGetDevice(&dev);
    int ncu = 0;
    if (hipDeviceGetAttribute(&ncu, hipDeviceAttributeMultiprocessorCount, dev) != hipSuccess || ncu <= 0)
        ncu = 256;
    int maxB = 0;
    if (hipOccupancyMaxActiveBlocksPerMultiprocessor(&maxB, (const void*)kfused, 256, 0) != hipSuccess || maxB <= 0)
        maxB = 1;
    long cap = (long)maxB * (long)ncu;
    int grd = (cap < 512) ? (int)(cap & ~7L) : 512;
    if (grd < 8) grd = 8;

    for (;;) {
        int nblk = grd >> 3;
        void* args[] = {
            (void*)&lengths, (void*)&eps, (void*)&W_ih, (void*)&b_ih, (void*)&b_hh,
            (void*)&W1a, (void*)&b1a, (void*)&W1b, (void*)&b1b,
            (void*)&W2a, (void*)&b2a, (void*)&W2b, (void*)&b2b,
            (void*)&out_p1, (void*)&out_p2, (void*)&out_h,
            (void*)&bar, (void*)&xT, (void*)&hT, (void*)&haT, (void*)&nblk
        };
        hipError_t err = hipLaunchCooperativeKernel((void*)kfused, dim3(grd), dim3(256), args, 0, stream);
        if (err == hipSuccess || grd <= 8) break;
        grd = (grd >> 1) & ~7;
        if (grd < 8) grd = 8;
    }
}